// Round 9
// baseline (349.671 us; speedup 1.0000x reference)
//
#include <hip/hip_runtime.h>
#include <cstdint>
#include <cstddef>

#define BATCH 4
#define NTOK  4096
#define CCH   256
#define IMH   512
#define IMW   512

#define ROWS_PER_BLOCK 4
#define NBLOCKS (BATCH * NTOK / ROWS_PER_BLOCK)   // 4096

// d_ws is 256 MiB. Stream = 2 passes over the SAME 256 MiB (in-bounds!).
#define WS_F4        (1u << 24)                    // 16,777,216 float4 = 256 MiB
#define STREAM_BYTES ((size_t)WS_F4 * 16)

typedef float v4f __attribute__((ext_vector_type(4)));

// ---------------------------------------------------------------------------
// ABLATION kernel (round 9 = round 8 with the OOB stream fixed). Each phase
// gated by a runtime `mode` bit; one codegen serves 4 launches:
//   mode 8  : stream only                          -> S
//   mode 9  : stream + scan                        -> S + a
//   mode 11 : stream + scan + gather               -> S + a + b
//   mode 15 : stream + scan + gather + dis (FULL)  -> S + a + b + c
// Stream pads every dispatch above the 43us harness fills so all four rows
// appear in top-5. Round 7 showed phases+stream are additive (53.3=25.3+28),
// so deltas are valid marginal costs. mode-15 launch writes the real d_out.
// ---------------------------------------------------------------------------
__global__ __launch_bounds__(256) void fused_abl_k(const float4* __restrict__ feat,
                                                   const float* __restrict__ im,
                                                   const int2* __restrict__ po,
                                                   const int4* __restrict__ ps4,
                                                   const v4f* __restrict__ stream_src,
                                                   float4* __restrict__ out_feat,
                                                   float* __restrict__ out_dis,
                                                   int mode) {
    __shared__ int s_key[ROWS_PER_BLOCK];
    __shared__ int s_idx[ROWS_PER_BLOCK];

    const int tid = threadIdx.x;
    const int r0  = blockIdx.x * ROWS_PER_BLOCK;
    const int b   = r0 >> 12;

    if (tid < ROWS_PER_BLOCK) {
        int2 p = po[r0 + tid];
        s_key[tid] = (p.x << 16) | p.y;
        s_idx[tid] = 0x7FFFFFFF;
    }
    __syncthreads();

    // --- phase 1: scan (mode bit 0) ---
    if (mode & 1) {
        int kreg[ROWS_PER_BLOCK];
#pragma unroll
        for (int k = 0; k < ROWS_PER_BLOCK; ++k) kreg[k] = s_key[k];

        const int4* psb = ps4 + (size_t)b * (NTOK / 2);
#pragma unroll
        for (int it = 0; it < NTOK / 2 / 256; ++it) {
            const int u = it * 256 + tid;
            const int4 v = psb[u];
            const int e0 = (v.x << 16) | v.y;
            const int e1 = (v.z << 16) | v.w;
            const int j0 = 2 * u;
#pragma unroll
            for (int k = 0; k < ROWS_PER_BLOCK; ++k) {
                if (e0 == kreg[k]) atomicMin(&s_idx[k], j0);
                if (e1 == kreg[k]) atomicMin(&s_idx[k], j0 + 1);
            }
        }
    }
    __syncthreads();

    // keep scan result live when no consumer phase runs (DCE guard, rule #17)
    if (!(mode & 2) && tid < ROWS_PER_BLOCK) {
        int t = s_idx[tid];
        asm volatile("" :: "v"(t));
    }

    const int lane = tid & 63;
    const int w    = tid >> 6;
    const int row = r0 + w;
    const int idx = s_idx[w];
    const int key = s_key[w];

    // --- phase 2a: gather (mode bit 1) ---
    if (mode & 2) {
        const v4f fv = __builtin_nontemporal_load(
            (const v4f*)&feat[((size_t)(b * NTOK + idx)) * 64 + lane]);
        __builtin_nontemporal_store(fv, (v4f*)&out_feat[(size_t)row * 64 + lane]);
    }

    // --- phase 2b: dis (mode bit 2) ---
    if (mode & 4) {
        float s = 0.f;
        if (lane < 48) {
            const int px  = key >> 16;
            const int py  = key & 0xFFFF;
            const int ch  = lane >> 4;
            const int k   = lane & 15;
            const int col = px * 4 + (k >> 2);
            const int r   = py * 4 + (k & 3);
            const float* base = im + (((size_t)(b * 3 + ch)) * IMH + r) * IMW + col;
            const float v = base[0];
            if (r > 0)         s += fabsf(v - base[-IMW]);
            if (r < IMH - 1)   s += fabsf(base[IMW] - v);
            if (col > 0)       s += fabsf(v - base[-1]);
            if (col < IMW - 1) s += fabsf(base[1] - v);
        }
        s += __shfl_xor(s, 1,  64);
        s += __shfl_xor(s, 2,  64);
        s += __shfl_xor(s, 4,  64);
        s += __shfl_xor(s, 8,  64);
        s += __shfl_xor(s, 16, 64);
        s += __shfl_xor(s, 32, 64);
        if (lane == 0) __builtin_nontemporal_store(s, &out_dis[row]);
    }

    // --- stream pad (mode bit 3): 2 passes over the SAME 256 MiB, in-bounds ---
    if ((mode & 8) && stream_src != nullptr) {
        const size_t base = (size_t)blockIdx.x * 4096;   // 4096 f4 per block
        v4f acc = {0.f, 0.f, 0.f, 0.f};
#pragma unroll
        for (int pass = 0; pass < 2; ++pass) {
#pragma unroll 4
            for (int r = 0; r < 16; ++r) {
                acc += __builtin_nontemporal_load(&stream_src[base + r * 256 + tid]);
            }
            asm volatile("" :: "v"(acc.x), "v"(acc.y), "v"(acc.z), "v"(acc.w));
        }
    }
}

extern "C" void kernel_launch(void* const* d_in, const int* in_sizes, int n_in,
                              void* d_out, int out_size, void* d_ws, size_t ws_size,
                              hipStream_t stream) {
    const float* feat         = (const float*)d_in[0];
    const float* images       = (const float*)d_in[1];
    const int*   pos_org      = (const int*)d_in[2];
    const int*   pos_shuffled = (const int*)d_in[3];

    float* out_feat = (float*)d_out;
    float* out_dis  = out_feat + (size_t)BATCH * NTOK * CCH;

    const v4f* ss = (ws_size >= STREAM_BYTES) ? (const v4f*)d_ws : nullptr;

    const int modes[4] = {8, 9, 11, 15};
    for (int m = 0; m < 4; ++m) {
        fused_abl_k<<<NBLOCKS, 256, 0, stream>>>(
            (const float4*)feat, images, (const int2*)pos_org,
            (const int4*)pos_shuffled, ss, (float4*)out_feat, out_dis, modes[m]);
    }
}

// Round 10
// 19.954 us; speedup vs baseline: 17.5234x; 17.5234x over previous
//
#include <hip/hip_runtime.h>
#include <cstdint>
#include <cstddef>

#define BATCH 4
#define NTOK  4096
#define CCH   256
#define IMH   512
#define IMW   512

#define RPB 8                                   // rows per block
#define NBLOCKS (BATCH * NTOK / RPB)            // 2048

typedef float v4f __attribute__((ext_vector_type(4)));

// ---------------------------------------------------------------------------
// MLP-restructured fused kernel (round 10).
// Theory from r7/r9 diagnostics: all phases were capped ~2-3 TB/s by per-wave
// memory-level parallelism of 1-2 (VGPR 12-28 -> load;waitcnt;use chains).
// Fixes: (1) scan = fully-unrolled 8-deep int4 load burst into registers
// before any consume; (2) 2 gather rows per wave = 2 independent row loads;
// (3) dis stencil loads unconditional (clamped offset + select) so all 5
// issue before the first waitcnt; (4) cached loads for L3-resident feat,
// nontemporal only for streaming stores.
// ---------------------------------------------------------------------------
__device__ __forceinline__ float dis48(const float* __restrict__ im,
                                       int b, int key, int lane) {
    float s = 0.f;
    if (lane < 48) {
        const int px  = key >> 16;
        const int py  = key & 0xFFFF;
        const int ch  = lane >> 4;
        const int k   = lane & 15;
        const int col = px * 4 + (k >> 2);      // x indexes columns
        const int r   = py * 4 + (k & 3);       // y indexes rows
        const float* base = im + (((size_t)(b * 3 + ch)) * IMH + r) * IMW + col;
        const bool up = (r > 0), dn = (r < IMH - 1);
        const bool lf = (col > 0), rt = (col < IMW - 1);
        // unconditional loads (clamped offsets) -> all 5 in flight together
        const float vC = base[0];
        const float vU = base[up ? -IMW : 0];
        const float vD = base[dn ?  IMW : 0];
        const float vL = base[lf ?   -1 : 0];
        const float vR = base[rt ?    1 : 0];
        s  = up ? fabsf(vC - vU) : 0.f;
        s += dn ? fabsf(vD - vC) : 0.f;
        s += lf ? fabsf(vC - vL) : 0.f;
        s += rt ? fabsf(vR - vC) : 0.f;
    }
    return s;
}

__global__ __launch_bounds__(256) void fused_k(const float4* __restrict__ feat,
                                               const float* __restrict__ im,
                                               const int2* __restrict__ po,
                                               const int4* __restrict__ ps4,
                                               float4* __restrict__ out_feat,
                                               float* __restrict__ out_dis) {
    __shared__ int s_key[RPB];
    __shared__ int s_idx[RPB];

    const int tid = threadIdx.x;
    const int r0  = blockIdx.x * RPB;           // 512 blocks per batch
    const int b   = r0 >> 12;

    if (tid < RPB) {
        int2 p = po[r0 + tid];
        s_key[tid] = (p.x << 16) | p.y;
        s_idx[tid] = 0x7FFFFFFF;
    }
    __syncthreads();

    // --- phase 1: scan. 8-deep independent load burst, then compare burst ---
    int kreg[RPB];
#pragma unroll
    for (int k = 0; k < RPB; ++k) kreg[k] = s_key[k];

    const int4* psb = ps4 + (size_t)b * (NTOK / 2);
    int4 t[8];
#pragma unroll
    for (int it = 0; it < 8; ++it) t[it] = psb[it * 256 + tid];   // all in flight

#pragma unroll
    for (int it = 0; it < 8; ++it) {
        const int e0 = (t[it].x << 16) | t[it].y;
        const int e1 = (t[it].z << 16) | t[it].w;
        const int j0 = 2 * (it * 256 + tid);
#pragma unroll
        for (int k = 0; k < RPB; ++k) {
            if (e0 == kreg[k]) atomicMin(&s_idx[k], j0);
            if (e1 == kreg[k]) atomicMin(&s_idx[k], j0 + 1);
        }
    }
    __syncthreads();

    // --- phase 2: gather + dis, TWO rows per wave (independent chains) ---
    const int lane = tid & 63;
    const int w    = tid >> 6;
    const int li0  = w * 2, li1 = w * 2 + 1;
    const int row0 = r0 + li0, row1 = r0 + li1;
    const int idx0 = s_idx[li0], idx1 = s_idx[li1];
    const int key0 = s_key[li0], key1 = s_key[li1];

    // issue both feat-row loads (cached; feat is L3-resident)
    const float4 f0 = feat[((size_t)(b * NTOK + idx0)) * 64 + lane];
    const float4 f1 = feat[((size_t)(b * NTOK + idx1)) * 64 + lane];

    // issue both stencil load sets
    float s0 = dis48(im, b, key0, lane);
    float s1 = dis48(im, b, key1, lane);

    // streaming stores
    v4f n0 = { f0.x, f0.y, f0.z, f0.w };
    v4f n1 = { f1.x, f1.y, f1.z, f1.w };
    __builtin_nontemporal_store(n0, (v4f*)&out_feat[(size_t)row0 * 64 + lane]);
    __builtin_nontemporal_store(n1, (v4f*)&out_feat[(size_t)row1 * 64 + lane]);

    // wave reduces (lanes 48..63 contribute 0)
#pragma unroll
    for (int d = 1; d < 64; d <<= 1) s0 += __shfl_xor(s0, d, 64);
#pragma unroll
    for (int d = 1; d < 64; d <<= 1) s1 += __shfl_xor(s1, d, 64);
    if (lane == 0) {
        __builtin_nontemporal_store(s0, &out_dis[row0]);
        __builtin_nontemporal_store(s1, &out_dis[row1]);
    }
}

extern "C" void kernel_launch(void* const* d_in, const int* in_sizes, int n_in,
                              void* d_out, int out_size, void* d_ws, size_t ws_size,
                              hipStream_t stream) {
    const float* feat         = (const float*)d_in[0];
    const float* images       = (const float*)d_in[1];
    const int*   pos_org      = (const int*)d_in[2];
    const int*   pos_shuffled = (const int*)d_in[3];

    float* out_feat = (float*)d_out;
    float* out_dis  = out_feat + (size_t)BATCH * NTOK * CCH;

    fused_k<<<NBLOCKS, 256, 0, stream>>>(
        (const float4*)feat, images, (const int2*)pos_org,
        (const int4*)pos_shuffled, (float4*)out_feat, out_dis);
}